// Round 5
// baseline (796.590 us; speedup 1.0000x reference)
//
#include <hip/hip_runtime.h>

#define NROWS 65536
#define FEA   512
#define MEM   2000
#define MEMP  2048
#define LAMBDA 0.0025f
#define EPS    1e-12f

#define PLX ((long)NROWS * FEA)   // elements per x plane
#define PLW ((long)MEMP * FEA)    // elements per W plane

typedef unsigned short ushort_t;
typedef __attribute__((ext_vector_type(8))) short bf16x8;
typedef __attribute__((ext_vector_type(16))) float f32x16;

// ---------- bf16 split helpers (RNE) ----------
__device__ inline ushort_t f2bf(float f) {
  unsigned int u = __float_as_uint(f);
  unsigned int r = (u + 0x7FFFu + ((u >> 16) & 1u)) >> 16;
  return (ushort_t)r;
}
__device__ inline float bf2f(ushort_t h) {
  return __uint_as_float(((unsigned int)h) << 16);
}

__device__ inline void gload_lds16(const void* g, void* l) {
  __builtin_amdgcn_global_load_lds(
      (const __attribute__((address_space(1))) unsigned int*)g,
      (__attribute__((address_space(3))) unsigned int*)l, 16, 0, 0);
}

// ------------------------------------------------------------------
// K0a: split x (fp32) -> xh, xl bf16 planes (stored in out region)
// ------------------------------------------------------------------
__global__ __launch_bounds__(256) void split_x(const float* __restrict__ x,
                                               ushort_t* __restrict__ xpl) {
  const long n4 = PLX / 4;
  long i = (long)blockIdx.x * 256 + threadIdx.x;
  const long stride = (long)gridDim.x * 256;
  for (; i < n4; i += stride) {
    float4 v = ((const float4*)x)[i];
    float f[4] = {v.x, v.y, v.z, v.w};
    ushort_t hh[4], ll[4];
#pragma unroll
    for (int j = 0; j < 4; ++j) {
      hh[j] = f2bf(f[j]);
      ll[j] = f2bf(f[j] - bf2f(hh[j]));
    }
    ushort4 h; h.x = hh[0]; h.y = hh[1]; h.z = hh[2]; h.w = hh[3];
    ushort4 l; l.x = ll[0]; l.y = ll[1]; l.z = ll[2]; l.w = ll[3];
    ((ushort4*)xpl)[i] = h;
    ((ushort4*)(xpl + PLX))[i] = l;
  }
}

// ------------------------------------------------------------------
// K0b: split W -> wh, wl planes, padded to 2048 rows (zeros)
// ------------------------------------------------------------------
__global__ __launch_bounds__(256) void split_w(const float* __restrict__ W,
                                               ushort_t* __restrict__ wpl) {
  long i = (long)blockIdx.x * 256 + threadIdx.x;
  if (i >= PLW / 4) return;
  long row = i / (FEA / 4);
  ushort4 h = {0, 0, 0, 0}, l = {0, 0, 0, 0};
  if (row < MEM) {
    float4 v = ((const float4*)W)[i];
    float f[4] = {v.x, v.y, v.z, v.w};
    ushort_t hh[4], ll[4];
#pragma unroll
    for (int j = 0; j < 4; ++j) {
      hh[j] = f2bf(f[j]);
      ll[j] = f2bf(f[j] - bf2f(hh[j]));
    }
    h.x = hh[0]; h.y = hh[1]; h.z = hh[2]; h.w = hh[3];
    l.x = ll[0]; l.y = ll[1]; l.z = ll[2]; l.w = ll[3];
  }
  ((ushort4*)wpl)[i] = h;
  ((ushort4*)(wpl + PLW))[i] = l;
}

// ------------------------------------------------------------------
// K1: S = x @ W^T, split-bf16 (3 products), 256x256 tile.
// SINGLE-WINDOW regions: {12 ds_reads | issue 4 gload_lds | 24 MFMA |
// [counted vmcnt] | one s_barrier}. Ring of 4 k-half slots/operand.
// vmcnt(4) only at odd regions (retires TWO slots), vmcnt(0) at r30.
// Slot: [256 rows][2 planes][16 k] bf16 = 64 B/row = 16 KB.
// Chunk swizzle: phys = c ^ ((row>>1)&3).
// ------------------------------------------------------------------
__device__ __forceinline__ void stageA(int j, int tid,
                                       const ushort_t* __restrict__ xpl,
                                       long rm0, ushort_t* ldsA) {
  ushort_t* dA = ldsA + (size_t)(j & 3) * 8192;
#pragma unroll
  for (int i = 0; i < 2; ++i) {
    int id = i * 512 + tid;
    int row = id >> 2;
    int c = (id & 3) ^ ((row >> 1) & 3);
    long goff = (long)(c >> 1) * PLX + (rm0 + row) * FEA + j * 16 + (c & 1) * 8;
    gload_lds16(xpl + goff, dA + id * 8);
  }
}
__device__ __forceinline__ void stageB(int j, int tid,
                                       const ushort_t* __restrict__ wpl,
                                       int cn0, ushort_t* ldsB) {
  ushort_t* dB = ldsB + (size_t)(j & 3) * 8192;
#pragma unroll
  for (int i = 0; i < 2; ++i) {
    int id = i * 512 + tid;
    int row = id >> 2;
    int c = (id & 3) ^ ((row >> 1) & 3);
    long goff = (long)(c >> 1) * PLW + (long)(cn0 + row) * FEA + j * 16 + (c & 1) * 8;
    gload_lds16(wpl + goff, dB + id * 8);
  }
}

// VM: -1 = barrier only, 4/0 = vmcnt(N)+barrier, -2 = nothing (last)
template <int SLOT, bool ISSUE, int VM>
__device__ __forceinline__ void region(
    int j3, int tid, int l32, int lh, int wm, int wn,
    const ushort_t* __restrict__ xpl, const ushort_t* __restrict__ wpl,
    long rm0, int cn0, ushort_t* ldsA, ushort_t* ldsB, f32x16 (&acc)[4][2]) {
  const ushort_t* As = ldsA + SLOT * 8192;
  const ushort_t* Bs = ldsB + SLOT * 8192;

  bf16x8 ah[4], al[4], bh[2], bl[2];
#pragma unroll
  for (int mf = 0; mf < 4; ++mf) {
    int r = wm * 128 + mf * 32 + l32;
    int sw = (r >> 1) & 3;
    ah[mf] = *(const bf16x8*)(As + r * 32 + ((lh ^ sw) * 8));
    al[mf] = *(const bf16x8*)(As + r * 32 + (((2 + lh) ^ sw) * 8));
  }
#pragma unroll
  for (int nf = 0; nf < 2; ++nf) {
    int r = wn * 64 + nf * 32 + l32;
    int sw = (r >> 1) & 3;
    bh[nf] = *(const bf16x8*)(Bs + r * 32 + ((lh ^ sw) * 8));
    bl[nf] = *(const bf16x8*)(Bs + r * 32 + (((2 + lh) ^ sw) * 8));
  }

  if constexpr (ISSUE) {
    stageA(j3, tid, xpl, rm0, ldsA);
    stageB(j3, tid, wpl, cn0, ldsB);
  }

  __builtin_amdgcn_s_setprio(1);
#pragma unroll
  for (int mf = 0; mf < 4; ++mf)
#pragma unroll
    for (int nf = 0; nf < 2; ++nf) {
      acc[mf][nf] = __builtin_amdgcn_mfma_f32_32x32x16_bf16(ah[mf], bh[nf], acc[mf][nf], 0, 0, 0);
      acc[mf][nf] = __builtin_amdgcn_mfma_f32_32x32x16_bf16(ah[mf], bl[nf], acc[mf][nf], 0, 0, 0);
      acc[mf][nf] = __builtin_amdgcn_mfma_f32_32x32x16_bf16(al[mf], bh[nf], acc[mf][nf], 0, 0, 0);
    }
  __builtin_amdgcn_s_setprio(0);

  if constexpr (VM == 4) asm volatile("s_waitcnt vmcnt(4)" ::: "memory");
  if constexpr (VM == 0) asm volatile("s_waitcnt vmcnt(0)" ::: "memory");
  if constexpr (VM != -2) asm volatile("s_barrier" ::: "memory");
}

__global__ __launch_bounds__(512, 2) void gemm_mfma3(
    const ushort_t* __restrict__ xpl, const ushort_t* __restrict__ wpl,
    float* __restrict__ S) {
  __shared__ alignas(16) ushort_t lds[65536];  // A ring 64 KB | B ring 64 KB
  ushort_t* ldsA = lds;
  ushort_t* ldsB = lds + 32768;

  const int tid = threadIdx.x;
  const int wid = tid >> 6, lane = tid & 63;
  const int l32 = lane & 31, lh = lane >> 5;
  const int wm = wid >> 2, wn = wid & 3;   // 2M x 4N waves

  // XCD-chunked bijective swizzle: 2048 wgs, each XCD owns 32 M-tiles x 8 N-tiles
  int wg = blockIdx.x;
  int xcd = wg & 7, idx = wg >> 3;
  const int mt = xcd * 32 + (idx >> 3);
  const int nt = idx & 7;
  const long rm0 = (long)mt * 256;
  const int cn0 = nt * 256;

  f32x16 acc[4][2] = {};

  // prologue: prefill k-halves 0..2 (12 loads/thread); slots 0,1 retired
  stageA(0, tid, xpl, rm0, ldsA); stageB(0, tid, wpl, cn0, ldsB);
  stageA(1, tid, xpl, rm0, ldsA); stageB(1, tid, wpl, cn0, ldsB);
  stageA(2, tid, xpl, rm0, ldsA); stageB(2, tid, wpl, cn0, ldsB);
  asm volatile("s_waitcnt vmcnt(4)" ::: "memory");
  asm volatile("s_barrier" ::: "memory");

  // 32 regions (16 K-tiles x 2 k-halves); j=0..27 in unroll-4 loop
  for (int t = 0; t < 7; ++t) {
    region<0, true, -1>(4 * t + 3, tid, l32, lh, wm, wn, xpl, wpl, rm0, cn0, ldsA, ldsB, acc);
    region<1, true,  4>(4 * t + 4, tid, l32, lh, wm, wn, xpl, wpl, rm0, cn0, ldsA, ldsB, acc);
    region<2, true, -1>(4 * t + 5, tid, l32, lh, wm, wn, xpl, wpl, rm0, cn0, ldsA, ldsB, acc);
    region<3, true,  4>(4 * t + 6, tid, l32, lh, wm, wn, xpl, wpl, rm0, cn0, ldsA, ldsB, acc);
  }
  region<0, true, -1>(31, tid, l32, lh, wm, wn, xpl, wpl, rm0, cn0, ldsA, ldsB, acc);  // j=28
  region<1, false, 4>(0,  tid, l32, lh, wm, wn, xpl, wpl, rm0, cn0, ldsA, ldsB, acc);  // j=29
  region<2, false, 0>(0,  tid, l32, lh, wm, wn, xpl, wpl, rm0, cn0, ldsA, ldsB, acc);  // j=30
  region<3, false, -2>(0, tid, l32, lh, wm, wn, xpl, wpl, rm0, cn0, ldsA, ldsB, acc);  // j=31

  // epilogue: C/D layout col=lane&31, row=(reg&3)+8*(reg>>2)+4*(lane>>5)
#pragma unroll
  for (int mf = 0; mf < 4; ++mf)
#pragma unroll
    for (int nf = 0; nf < 2; ++nf) {
      int col = cn0 + wn * 64 + nf * 32 + l32;
      if (col < MEM) {
        long rbase = rm0 + wm * 128 + mf * 32 + 4 * lh;
#pragma unroll
        for (int r = 0; r < 16; ++r) {
          long row = rbase + (r & 3) + 8 * (r >> 2);
          S[row * MEM + col] = acc[mf][nf][r];
        }
      }
    }
}

// ------------------------------------------------------------------
// Fallback fp32 GEMM (used only if ws too small)
// ------------------------------------------------------------------
#define BK 32
__global__ __launch_bounds__(256) void gemm_scores(
    const float* __restrict__ x, const float* __restrict__ Wt,
    float* __restrict__ S) {
  __shared__ float xs[BK][129];
  __shared__ float ws[BK][129];
  const int tid = threadIdx.x;
  const int rm0 = blockIdx.x * 128;
  const int cn0 = blockIdx.y * 128;
  const int tx = tid & 15, ty = tid >> 4;
  const int sr = tid >> 3, kq = tid & 7;
  float acc[8][8];
#pragma unroll
  for (int i = 0; i < 8; ++i)
#pragma unroll
    for (int j = 0; j < 8; ++j) acc[i][j] = 0.f;
  for (int k0 = 0; k0 < FEA; k0 += BK) {
#pragma unroll
    for (int b = 0; b < 4; ++b) {
      const int row = sr + 32 * b;
      float4 v = *(const float4*)(x + (size_t)(rm0 + row) * FEA + k0 + kq * 4);
      xs[kq * 4 + 0][row] = v.x; xs[kq * 4 + 1][row] = v.y;
      xs[kq * 4 + 2][row] = v.z; xs[kq * 4 + 3][row] = v.w;
      int wr = cn0 + row; wr = (wr < MEM) ? wr : (MEM - 1);
      float4 u = *(const float4*)(Wt + (size_t)wr * FEA + k0 + kq * 4);
      ws[kq * 4 + 0][row] = u.x; ws[kq * 4 + 1][row] = u.y;
      ws[kq * 4 + 2][row] = u.z; ws[kq * 4 + 3][row] = u.w;
    }
    __syncthreads();
#pragma unroll 8
    for (int k = 0; k < BK; ++k) {
      float a[8], bb[8];
      float4 t0 = *(const float4*)&xs[k][4 * ty];
      float4 t1 = *(const float4*)&xs[k][64 + 4 * ty];
      a[0] = t0.x; a[1] = t0.y; a[2] = t0.z; a[3] = t0.w;
      a[4] = t1.x; a[5] = t1.y; a[6] = t1.z; a[7] = t1.w;
      float4 u0 = *(const float4*)&ws[k][4 * tx];
      float4 u1 = *(const float4*)&ws[k][64 + 4 * tx];
      bb[0] = u0.x; bb[1] = u0.y; bb[2] = u0.z; bb[3] = u0.w;
      bb[4] = u1.x; bb[5] = u1.y; bb[6] = u1.z; bb[7] = u1.w;
#pragma unroll
      for (int i = 0; i < 8; ++i)
#pragma unroll
        for (int j = 0; j < 8; ++j)
          acc[i][j] = fmaf(a[i], bb[j], acc[i][j]);
    }
    __syncthreads();
  }
#pragma unroll
  for (int i = 0; i < 8; ++i) {
    const int row = rm0 + ((i < 4) ? (4 * ty + i) : (64 + 4 * ty + (i - 4)));
    const int c0 = cn0 + 4 * tx;
    const int c1 = cn0 + 64 + 4 * tx;
    if (c0 < MEM) {
      float4 v; v.x = acc[i][0]; v.y = acc[i][1]; v.z = acc[i][2]; v.w = acc[i][3];
      *(float4*)(S + (size_t)row * MEM + c0) = v;
    }
    if (c1 < MEM) {
      float4 v; v.x = acc[i][4]; v.y = acc[i][5]; v.z = acc[i][6]; v.w = acc[i][7];
      *(float4*)(S + (size_t)row * MEM + c1) = v;
    }
  }
}

// ------------------------------------------------------------------
// K2: softmax -> hard shrink -> renorm -> write att + sparse out
// ------------------------------------------------------------------
__global__ __launch_bounds__(512) void softmax_shrink_out(
    const float* __restrict__ Wt, float* __restrict__ out,
    float* __restrict__ att /* raw scores on entry */) {
  __shared__ float sl[8 * MEM];
  const int tid = threadIdx.x;
  const int r0 = blockIdx.x * 8;
  {
    const float* Sblk = att + (size_t)r0 * MEM;
#pragma unroll
    for (int jj = 0; jj < 8; ++jj) {
      int q = tid + 512 * jj;
      if (q < (8 * MEM) / 4) {
        float4 v = *(const float4*)(Sblk + 4 * q);
        *(float4*)&sl[4 * q] = v;
      }
    }
  }
  __syncthreads();
  const int w = tid >> 6;
  const int l = tid & 63;
  float* row_lds = &sl[w * MEM];
  const int grow = r0 + w;

  float m = -INFINITY;
  for (int j = 0; j < 32; ++j) {
    int c = l + 64 * j;
    if (c < MEM) m = fmaxf(m, row_lds[c]);
  }
#pragma unroll
  for (int off = 32; off; off >>= 1) m = fmaxf(m, __shfl_xor(m, off));

  float s = 0.f;
  for (int j = 0; j < 32; ++j) {
    int c = l + 64 * j;
    if (c < MEM) {
      float e = expf(row_lds[c] - m);
      row_lds[c] = e;
      s += e;
    }
  }
#pragma unroll
  for (int off = 32; off; off >>= 1) s += __shfl_xor(s, off);

  float qs = 0.f;
  for (int j = 0; j < 32; ++j) {
    int c = l + 64 * j;
    if (c < MEM) {
      float p = row_lds[c] / s;
      float d = p - LAMBDA;
      float q = fmaxf(d, 0.f) * p / (fabsf(d) + EPS);
      row_lds[c] = q;
      qs += q;
    }
  }
#pragma unroll
  for (int off = 32; off; off >>= 1) qs += __shfl_xor(qs, off);
  const float denom = fmaxf(qs, EPS);

  float4 oa0 = {0.f, 0.f, 0.f, 0.f};
  float4 oa1 = {0.f, 0.f, 0.f, 0.f};
  for (int j = 0; j < 32; ++j) {
    int c = l + 64 * j;
    float a = 0.f;
    if (c < MEM) {
      a = row_lds[c] / denom;
      att[(size_t)grow * MEM + c] = a;
    }
    unsigned long long msk = __ballot(a > 0.f);
    while (msk) {
      int b = __ffsll(msk) - 1;
      msk &= msk - 1;
      float av = __shfl(a, b);
      int cc = b + 64 * j;
      const float* wp = Wt + (size_t)cc * FEA;
      float4 w0 = *(const float4*)(wp + 4 * l);
      float4 w1 = *(const float4*)(wp + 256 + 4 * l);
      oa0.x = fmaf(av, w0.x, oa0.x); oa0.y = fmaf(av, w0.y, oa0.y);
      oa0.z = fmaf(av, w0.z, oa0.z); oa0.w = fmaf(av, w0.w, oa0.w);
      oa1.x = fmaf(av, w1.x, oa1.x); oa1.y = fmaf(av, w1.y, oa1.y);
      oa1.z = fmaf(av, w1.z, oa1.z); oa1.w = fmaf(av, w1.w, oa1.w);
    }
  }
  float* op = out + (size_t)grow * FEA;
  *(float4*)(op + 4 * l) = oa0;
  *(float4*)(op + 256 + 4 * l) = oa1;
}

// ------------------------------------------------------------------
extern "C" void kernel_launch(void* const* d_in, const int* in_sizes, int n_in,
                              void* d_out, int out_size, void* d_ws, size_t ws_size,
                              hipStream_t stream) {
  (void)in_sizes; (void)n_in; (void)out_size;
  const float* x = (const float*)d_in[0];
  const float* W = (const float*)d_in[1];
  float* out = (float*)d_out;
  float* att = (float*)d_out + (size_t)NROWS * FEA;

  const size_t w_need = (size_t)PLW * 2 * sizeof(ushort_t);  // 4 MB
  if (ws_size >= w_need) {
    ushort_t* xpl = (ushort_t*)d_out;  // out region: exactly fits 2 x-planes
    ushort_t* wpl = (ushort_t*)d_ws;
    split_x<<<2048, 256, 0, stream>>>(x, xpl);
    split_w<<<(int)(PLW / 4 / 256), 256, 0, stream>>>(W, wpl);
    gemm_mfma3<<<2048, 512, 0, stream>>>(xpl, wpl, att);
  } else {
    dim3 g1(NROWS / 128, (MEM + 127) / 128);
    gemm_scores<<<g1, 256, 0, stream>>>(x, W, att);
  }
  softmax_shrink_out<<<NROWS / 8, 512, 0, stream>>>(W, out, att);
}